// Round 4
// baseline (154.414 us; speedup 1.0000x reference)
//
#include <hip/hip_runtime.h>
#include <cstdint>
#include <cstddef>

// Problem constants (fixed by the reference: N=4096, D=512)
constexpr int N_ROWS = 4096;
constexpr int D      = 512;
constexpr int M      = 8192;   // 2N
constexpr int NTILE  = 64;     // M / 128
constexpr int NBLK   = NTILE * (NTILE + 1) / 2;   // 2080 upper-tri tile pairs
constexpr int BK     = 64;     // K-chunk per LDS buffer

using f32x4  = __attribute__((ext_vector_type(4))) float;
using bf16x8 = __attribute__((ext_vector_type(8))) __bf16;
using us8    = __attribute__((ext_vector_type(8))) unsigned short;

// RNE float -> bf16 (inputs are finite, no NaN handling needed)
__device__ inline unsigned short f2bf(float f) {
    unsigned int u = __float_as_uint(f);
    u += 0x7fffu + ((u >> 16) & 1u);
    return (unsigned short)(u >> 16);
}
__device__ inline float bf2f(unsigned short s) {
    return __uint_as_float(((unsigned int)s) << 16);
}

// 16B async global->LDS copy. LDS dest is wave-uniform base + lane*16.
#define ASYNC_CP16(gsrc, ldst)                                                      \
    __builtin_amdgcn_global_load_lds(                                               \
        (const __attribute__((address_space(1))) unsigned int*)(gsrc),              \
        (__attribute__((address_space(3))) unsigned int*)(ldst), 16, 0, 0)

// ---------------------------------------------------------------------------
// Kernel 1: fused normalize + positive-pair logits.
// One wave handles PAIR k: row k (emb_i) and row k+N (emb_j).
// ---------------------------------------------------------------------------
__global__ __launch_bounds__(256) void normpos_kernel(
    const float* __restrict__ emb_i, const float* __restrict__ emb_j,
    unsigned short* __restrict__ zb, float* __restrict__ rowsum,
    float* __restrict__ diagss, float* __restrict__ pos)
{
    const int wave = threadIdx.x >> 6, lane = threadIdx.x & 63;
    const int k = blockIdx.x * 4 + wave;

    const float4* a = (const float4*)(emb_i + (size_t)k * D);
    const float4* b = (const float4*)(emb_j + (size_t)k * D);
    float4 a0 = a[lane * 2], a1 = a[lane * 2 + 1];
    float4 b0 = b[lane * 2], b1 = b[lane * 2 + 1];

    float ssi = a0.x*a0.x + a0.y*a0.y + a0.z*a0.z + a0.w*a0.w
              + a1.x*a1.x + a1.y*a1.y + a1.z*a1.z + a1.w*a1.w;
    float ssj = b0.x*b0.x + b0.y*b0.y + b0.z*b0.z + b0.w*b0.w
              + b1.x*b1.x + b1.y*b1.y + b1.z*b1.z + b1.w*b1.w;
    float dp  = a0.x*b0.x + a0.y*b0.y + a0.z*b0.z + a0.w*b0.w
              + a1.x*b1.x + a1.y*b1.y + a1.z*b1.z + a1.w*b1.w;
    #pragma unroll
    for (int off = 32; off; off >>= 1) {
        ssi += __shfl_xor(ssi, off, 64);
        ssj += __shfl_xor(ssj, off, 64);
        dp  += __shfl_xor(dp,  off, 64);
    }
    const float invi = rsqrtf(ssi), invj = rsqrtf(ssj);

    const float zi[8] = {a0.x*invi, a0.y*invi, a0.z*invi, a0.w*invi,
                         a1.x*invi, a1.y*invi, a1.z*invi, a1.w*invi};
    const float zj[8] = {b0.x*invj, b0.y*invj, b0.z*invj, b0.w*invj,
                         b1.x*invj, b1.y*invj, b1.z*invj, b1.w*invj};
    us8 pi, pj;
    float dssi = 0.f, dssj = 0.f;
    #pragma unroll
    for (int t = 0; t < 8; ++t) {
        unsigned short bi = f2bf(zi[t]), bj = f2bf(zj[t]);
        pi[t] = bi; pj[t] = bj;
        float fi = bf2f(bi), fj = bf2f(bj);
        dssi += fi * fi; dssj += fj * fj;
    }
    *(us8*)(zb + (size_t)k * D + lane * 8)            = pi;
    *(us8*)(zb + (size_t)(k + N_ROWS) * D + lane * 8) = pj;
    #pragma unroll
    for (int off = 32; off; off >>= 1) {
        dssi += __shfl_xor(dssi, off, 64);
        dssj += __shfl_xor(dssj, off, 64);
    }
    if (lane == 0) {
        rowsum[k]          = 0.0f;
        rowsum[k + N_ROWS] = 0.0f;
        diagss[k]          = dssi;
        diagss[k + N_ROWS] = dssj;
        pos[k]             = 2.0f * dp * invi * invj;
    }
}

// ---------------------------------------------------------------------------
// Kernel 2: symmetric fused sim-GEMM + exp + row/col sums.
// Upper-triangle tile pairs (bi <= bj), 2080 blocks. 128x128 tile, 4 waves
// 2x2, BK=64, DOUBLE-BUFFERED LDS: prefetch for iter k+1 is issued right
// after the barrier, so the compiler's vmcnt(0) drain at the next barrier
// lands after a full compute phase has covered most of the load latency
// (round-3 structure exposed full latency every iter -> MfmaUtil 18%).
// One barrier per iteration. 8-chunk XOR swizzle (chunk ^ (row&7)).
// NO device-scope fences (round-2 lesson: they thrash per-XCD L2).
// ---------------------------------------------------------------------------
__global__ __launch_bounds__(256, 2) void simgemm_kernel(
    const unsigned short* __restrict__ zb, float* __restrict__ rowsum)
{
    __shared__ unsigned short As[2][128 * BK];   // 32 KB
    __shared__ unsigned short Bs[2][128 * BK];   // 32 KB
    const int tid  = threadIdx.x;
    const int wave = tid >> 6, lane = tid & 63;
    const int l15  = lane & 15, ks = lane >> 4;

    // Decode linear block id -> (bi, bj), bi <= bj. cum(bi) = bi*(129-bi)/2.
    const int t = blockIdx.x;
    int bi = (int)((129.0f - sqrtf(129.0f * 129.0f - 8.0f * (float)t)) * 0.5f);
    while (bi > 0 && bi * (129 - bi) / 2 > t) --bi;
    while ((bi + 1) * (129 - (bi + 1)) / 2 <= t) ++bi;
    const int bj = bi + (t - bi * (129 - bi) / 2);
    const bool diag = (bi == bj);

    const int wrow = (wave >> 1) * 64, wcol = (wave & 1) * 64;

    // Staging: wave w owns rows [w*32, w*32+32), 4 asyncs per matrix per iter.
    // Async c covers rows w*32+c*8 .. +8; lane l -> row +l/8, phys 16B chunk
    // l%8. Source chunk = (l%8) ^ (row&7) = (l%8) ^ (l/8)  (8-chunk swizzle).
    const int srow = wave * 32 + (lane >> 3);
    const int scol = ((lane & 7) ^ (lane >> 3)) * 8;        // elems in [0,64)
    const unsigned short* gA = zb + (size_t)(bi * 128 + srow) * D + scol;
    const unsigned short* gB = zb + (size_t)(bj * 128 + srow) * D + scol;

    f32x4 acc[4][4] = {};
    const int swz0 = (ks ^ (l15 & 7)) * 8;         // s=0 frag offset (elems)
    const int swz1 = ((ks + 4) ^ (l15 & 7)) * 8;   // s=1

    // Prime buffer 0
    {
        unsigned short* dA = &As[0][wave * 32 * BK];
        unsigned short* dB = &Bs[0][wave * 32 * BK];
        #pragma unroll
        for (int c = 0; c < 4; ++c) {
            ASYNC_CP16(gA + (size_t)c * 8 * D, dA + c * 8 * BK);
            ASYNC_CP16(gB + (size_t)c * 8 * D, dB + c * 8 * BK);
        }
    }

    #pragma unroll
    for (int it = 0; it < D / BK; ++it) {
        __syncthreads();   // vmcnt(0) drain: buffer (it&1) ready

        if (it + 1 < D / BK) {   // prefetch next tile into the other buffer
            const int nb = (it + 1) & 1;
            const int kc = (it + 1) * BK;
            unsigned short* dA = &As[nb][wave * 32 * BK];
            unsigned short* dB = &Bs[nb][wave * 32 * BK];
            #pragma unroll
            for (int c = 0; c < 4; ++c) {
                ASYNC_CP16(gA + kc + (size_t)c * 8 * D, dA + c * 8 * BK);
                ASYNC_CP16(gB + kc + (size_t)c * 8 * D, dB + c * 8 * BK);
            }
        }

        const int cb = it & 1;
        #pragma unroll
        for (int s = 0; s < 2; ++s) {
            const int so = s ? swz1 : swz0;
            bf16x8 af[4], bg[4];
            #pragma unroll
            for (int f = 0; f < 4; ++f) {
                af[f] = *(const bf16x8*)(&As[cb][(wrow + f * 16 + l15) * BK + so]);
                bg[f] = *(const bf16x8*)(&Bs[cb][(wcol + f * 16 + l15) * BK + so]);
            }
            #pragma unroll
            for (int i = 0; i < 4; ++i)
                #pragma unroll
                for (int j = 0; j < 4; ++j)
                    acc[i][j] = __builtin_amdgcn_mfma_f32_16x16x32_bf16(
                        af[i], bg[j], acc[i][j], 0, 0, 0);
        }
    }

    // Epilogue. C/D layout: row = ks*4 + r, col = l15 (within each 16x16).
    // e = exp(sim/T) = exp(2*acc); feeds row-partials and (off-diag) the
    // symmetric column-partials, from registers.
    float rowp[4][4] = {};
    float* rsA = rowsum + bi * 128 + wrow;
    float* rsB = rowsum + bj * 128 + wcol;
    #pragma unroll
    for (int j = 0; j < 4; ++j) {
        float cp = 0.f;
        #pragma unroll
        for (int i = 0; i < 4; ++i)
            #pragma unroll
            for (int r = 0; r < 4; ++r) {
                float e = __expf(2.0f * acc[i][j][r]);
                rowp[i][r] += e;
                cp += e;
            }
        if (!diag) {
            cp += __shfl_xor(cp, 16, 64);
            cp += __shfl_xor(cp, 32, 64);
            if (ks == 0) atomicAdd(rsB + j * 16 + l15, cp);
        }
    }
    #pragma unroll
    for (int i = 0; i < 4; ++i)
        #pragma unroll
        for (int r = 0; r < 4; ++r) {
            float e = rowp[i][r];
            e += __shfl_xor(e, 1, 64);
            e += __shfl_xor(e, 2, 64);
            e += __shfl_xor(e, 4, 64);
            e += __shfl_xor(e, 8, 64);
            if (l15 == 0) atomicAdd(rsA + i * 16 + ks * 4 + r, e);
        }
}

// ---------------------------------------------------------------------------
// Kernel 3: loss = [ sum_i log(rowsum_i - exp(2*diagss_i)) - 2*sum_k pos_k ] / 8192
// ---------------------------------------------------------------------------
__global__ __launch_bounds__(1024) void finalize_kernel(
    const float* __restrict__ rowsum, const float* __restrict__ diagss,
    const float* __restrict__ pos, float* __restrict__ out)
{
    float local = 0.f;
    for (int i = threadIdx.x; i < M; i += 1024)
        local += __logf(rowsum[i] - __expf(2.0f * diagss[i]));
    for (int k = threadIdx.x; k < N_ROWS; k += 1024)
        local -= 2.0f * pos[k];
    #pragma unroll
    for (int off = 32; off; off >>= 1) local += __shfl_xor(local, off, 64);
    __shared__ float red[16];
    const int wave = threadIdx.x >> 6, lane = threadIdx.x & 63;
    if (lane == 0) red[wave] = local;
    __syncthreads();
    if (threadIdx.x == 0) {
        float t = 0.f;
        #pragma unroll
        for (int w = 0; w < 16; ++w) t += red[w];
        out[0] = t * (1.0f / 8192.0f);
    }
}

// ---------------------------------------------------------------------------
extern "C" void kernel_launch(void* const* d_in, const int* in_sizes, int n_in,
                              void* d_out, int out_size, void* d_ws, size_t ws_size,
                              hipStream_t stream)
{
    const float* emb_i = (const float*)d_in[0];
    const float* emb_j = (const float*)d_in[1];

    // ws layout: zb bf16 [M][D] (8 MB) | rowsum f32[M] | diagss f32[M]
    //            | pos f32[N]   (~8.4 MB total)
    unsigned short* zb = (unsigned short*)d_ws;
    float* rowsum = (float*)((char*)d_ws + (size_t)M * D * sizeof(unsigned short));
    float* diagss = rowsum + M;
    float* pos    = diagss + M;
    float* out    = (float*)d_out;

    normpos_kernel<<<N_ROWS / 4, 256, 0, stream>>>(emb_i, emb_j, zb, rowsum,
                                                   diagss, pos);
    simgemm_kernel<<<NBLK, 256, 0, stream>>>(zb, rowsum);
    finalize_kernel<<<1, 1024, 0, stream>>>(rowsum, diagss, pos, out);
}

// Round 6
// 125.979 us; speedup vs baseline: 1.2257x; 1.2257x over previous
//
#include <hip/hip_runtime.h>
#include <cstdint>
#include <cstddef>

// Problem constants (fixed by the reference: N=4096, D=512)
constexpr int N_ROWS = 4096;
constexpr int D      = 512;
constexpr int M      = 8192;   // 2N
constexpr int NTILE  = 64;     // M / 128
constexpr int NBLK   = NTILE * (NTILE + 1) / 2;   // 2080 upper-tri tile pairs

using f32x4  = __attribute__((ext_vector_type(4))) float;
using bf16x8 = __attribute__((ext_vector_type(8))) __bf16;
using us8    = __attribute__((ext_vector_type(8))) unsigned short;

// RNE float -> bf16 (inputs are finite, no NaN handling needed)
__device__ inline unsigned short f2bf(float f) {
    unsigned int u = __float_as_uint(f);
    u += 0x7fffu + ((u >> 16) & 1u);
    return (unsigned short)(u >> 16);
}
__device__ inline float bf2f(unsigned short s) {
    return __uint_as_float(((unsigned int)s) << 16);
}

// 16B async global->LDS copy. LDS dest is wave-uniform base + lane*16.
#define ASYNC_CP16(gsrc, ldst)                                                      \
    __builtin_amdgcn_global_load_lds(                                               \
        (const __attribute__((address_space(1))) unsigned int*)(gsrc),              \
        (__attribute__((address_space(3))) unsigned int*)(ldst), 16, 0, 0)

// ---------------------------------------------------------------------------
// Kernel 1: fused normalize + positive-pair logits.
// One wave handles PAIR k: row k (emb_i) and row k+N (emb_j).
// ---------------------------------------------------------------------------
__global__ __launch_bounds__(256) void normpos_kernel(
    const float* __restrict__ emb_i, const float* __restrict__ emb_j,
    unsigned short* __restrict__ zb, float* __restrict__ diagss,
    float* __restrict__ pos)
{
    const int wave = threadIdx.x >> 6, lane = threadIdx.x & 63;
    const int k = blockIdx.x * 4 + wave;

    const float4* a = (const float4*)(emb_i + (size_t)k * D);
    const float4* b = (const float4*)(emb_j + (size_t)k * D);
    float4 a0 = a[lane * 2], a1 = a[lane * 2 + 1];
    float4 b0 = b[lane * 2], b1 = b[lane * 2 + 1];

    float ssi = a0.x*a0.x + a0.y*a0.y + a0.z*a0.z + a0.w*a0.w
              + a1.x*a1.x + a1.y*a1.y + a1.z*a1.z + a1.w*a1.w;
    float ssj = b0.x*b0.x + b0.y*b0.y + b0.z*b0.z + b0.w*b0.w
              + b1.x*b1.x + b1.y*b1.y + b1.z*b1.z + b1.w*b1.w;
    float dp  = a0.x*b0.x + a0.y*b0.y + a0.z*b0.z + a0.w*b0.w
              + a1.x*b1.x + a1.y*b1.y + a1.z*b1.z + a1.w*b1.w;
    #pragma unroll
    for (int off = 32; off; off >>= 1) {
        ssi += __shfl_xor(ssi, off, 64);
        ssj += __shfl_xor(ssj, off, 64);
        dp  += __shfl_xor(dp,  off, 64);
    }
    const float invi = rsqrtf(ssi), invj = rsqrtf(ssj);

    const float zi[8] = {a0.x*invi, a0.y*invi, a0.z*invi, a0.w*invi,
                         a1.x*invi, a1.y*invi, a1.z*invi, a1.w*invi};
    const float zj[8] = {b0.x*invj, b0.y*invj, b0.z*invj, b0.w*invj,
                         b1.x*invj, b1.y*invj, b1.z*invj, b1.w*invj};
    us8 pi, pj;
    float dssi = 0.f, dssj = 0.f;
    #pragma unroll
    for (int t = 0; t < 8; ++t) {
        unsigned short bi = f2bf(zi[t]), bj = f2bf(zj[t]);
        pi[t] = bi; pj[t] = bj;
        float fi = bf2f(bi), fj = bf2f(bj);
        dssi += fi * fi; dssj += fj * fj;
    }
    *(us8*)(zb + (size_t)k * D + lane * 8)            = pi;
    *(us8*)(zb + (size_t)(k + N_ROWS) * D + lane * 8) = pj;
    #pragma unroll
    for (int off = 32; off; off >>= 1) {
        dssi += __shfl_xor(dssi, off, 64);
        dssj += __shfl_xor(dssj, off, 64);
    }
    if (lane == 0) {
        diagss[k]          = dssi;
        diagss[k + N_ROWS] = dssj;
        pos[k]             = 2.0f * dp * invi * invj;
    }
}

// ---------------------------------------------------------------------------
// Kernel 2: symmetric fused sim-GEMM + exp + row/col partial sums.
// Upper-triangle tile pairs (bi <= bj), 2080 blocks. 128x128 tile, 4 waves
// 2x2, BK=32, single-buffered (round-4 dbuf regressed: LDS 64KB halved
// occupancy, compute phase too short to cover latency anyway).
// ZERO global atomics (round-3 lesson: device-scope atomics bounce lines
// across 8 XCDs). Waves sharing output rows/cols are combined through LDS
// (round-5 bug: two waves share each 64-row half -> plain stores raced).
// Each block then stores exactly-once to its private partial slots:
// A-side rows -> partials[bi][bj][0..127], B-side cols -> partials[bj][bi].
// ---------------------------------------------------------------------------
__global__ __launch_bounds__(256, 4) void simgemm_kernel(
    const unsigned short* __restrict__ zb, float* __restrict__ partials)
{
    __shared__ unsigned short As[128 * 32];
    __shared__ unsigned short Bs[128 * 32];
    __shared__ float rp[4][64];    // per-wave row partials
    __shared__ float cp4[4][64];   // per-wave col partials
    const int tid  = threadIdx.x;
    const int wave = tid >> 6, lane = tid & 63;
    const int l15  = lane & 15, ks = lane >> 4;

    // Decode linear block id -> (bi, bj), bi <= bj. cum(bi) = bi*(129-bi)/2.
    const int t = blockIdx.x;
    int bi = (int)((129.0f - sqrtf(129.0f * 129.0f - 8.0f * (float)t)) * 0.5f);
    while (bi > 0 && bi * (129 - bi) / 2 > t) --bi;
    while ((bi + 1) * (129 - (bi + 1)) / 2 <= t) ++bi;
    const int bj = bi + (t - bi * (129 - bi) / 2);
    const bool diag = (bi == bj);

    const int wrow = (wave >> 1) * 64, wcol = (wave & 1) * 64;

    // Staging mapping: tile = 8 chunks of 1024B (16 rows each); wave w owns
    // chunks {2w, 2w+1}. lane l -> row chunk*16 + (l>>2), phys 16B slot l&3.
    const int ch0 = wave * 2;
    const int sr0 = ch0 * 16 + (lane >> 2);
    const int sc  = ((lane & 3) ^ ((sr0 >> 1) & 3)) * 8;   // swizzled k-offset (elems)
    const unsigned short* gA0 = zb + (size_t)(bi * 128 + sr0) * D + sc;
    const unsigned short* gB0 = zb + (size_t)(bj * 128 + sr0) * D + sc;
    unsigned short* lA0 = As + ch0 * 512;
    unsigned short* lA1 = As + ch0 * 512 + 512;
    unsigned short* lB0 = Bs + ch0 * 512;
    unsigned short* lB1 = Bs + ch0 * 512 + 512;

    f32x4 acc[4][4] = {};
    const int swOff = (ks ^ ((l15 >> 1) & 3)) * 8;  // swizzled frag k-offset (elems)

    for (int kc = 0; kc < D; kc += 32) {
        ASYNC_CP16(gA0 + kc,          lA0);
        ASYNC_CP16(gA0 + kc + 16 * D, lA1);
        ASYNC_CP16(gB0 + kc,          lB0);
        ASYNC_CP16(gB0 + kc + 16 * D, lB1);
        __syncthreads();

        bf16x8 af[4], bg[4];
        #pragma unroll
        for (int f = 0; f < 4; ++f) {
            af[f] = *(const bf16x8*)(As + (wrow + f * 16 + l15) * 32 + swOff);
            bg[f] = *(const bf16x8*)(Bs + (wcol + f * 16 + l15) * 32 + swOff);
        }
        #pragma unroll
        for (int i = 0; i < 4; ++i)
            #pragma unroll
            for (int j = 0; j < 4; ++j)
                acc[i][j] = __builtin_amdgcn_mfma_f32_16x16x32_bf16(
                    af[i], bg[j], acc[i][j], 0, 0, 0);
        __syncthreads();
    }

    // Epilogue. C/D layout: row = ks*4 + r, col = l15 (within each 16x16).
    // e = exp(sim/T) = exp(2*acc). Per-wave partials -> LDS, combine the two
    // waves sharing each row-half / col-half, store exactly once.
    float rowp[4][4] = {};
    #pragma unroll
    for (int j = 0; j < 4; ++j) {
        float cpj = 0.f;
        #pragma unroll
        for (int i = 0; i < 4; ++i)
            #pragma unroll
            for (int r = 0; r < 4; ++r) {
                float e = __expf(2.0f * acc[i][j][r]);
                rowp[i][r] += e;
                cpj += e;
            }
        if (!diag) {
            cpj += __shfl_xor(cpj, 16, 64);
            cpj += __shfl_xor(cpj, 32, 64);
            if (ks == 0) cp4[wave][j * 16 + l15] = cpj;
        }
    }
    #pragma unroll
    for (int i = 0; i < 4; ++i)
        #pragma unroll
        for (int r = 0; r < 4; ++r) {
            float e = rowp[i][r];
            e += __shfl_xor(e, 1, 64);
            e += __shfl_xor(e, 2, 64);
            e += __shfl_xor(e, 4, 64);
            e += __shfl_xor(e, 8, 64);
            if (l15 == 0) rp[wave][i * 16 + ks * 4 + r] = e;
        }
    __syncthreads();

    // rows 0-63 from waves {0,1}, 64-127 from {2,3};
    // cols 0-63 from waves {0,2}, 64-127 from {1,3}.
    float* pA = partials + (size_t)(bi * NTILE + bj) * 128;
    float* pB = partials + (size_t)(bj * NTILE + bi) * 128;
    if (tid < 128) {
        const int h = tid >> 6, rr = tid & 63;
        pA[tid] = rp[h * 2][rr] + rp[h * 2 + 1][rr];
    } else if (!diag) {
        const int c = tid - 128, h = c >> 6, cc = c & 63;
        pB[c] = cp4[h][cc] + cp4[h + 2][cc];
    }
}

// ---------------------------------------------------------------------------
// Kernel 3: per-tile-row reduction of partials + log terms.
// Block r: rowsum[row] = sum_c partials[r][c][row&127]; lgpart[r] =
// sum_row log(rowsum - exp(2*diagss)). Fully coalesced, no atomics.
// ---------------------------------------------------------------------------
__global__ __launch_bounds__(256) void rowfin_kernel(
    const float* __restrict__ partials, const float* __restrict__ diagss,
    float* __restrict__ lgpart)
{
    const int r  = blockIdx.x;          // tile-row 0..63
    const int ri = threadIdx.x & 127;   // row within tile
    const int ch = threadIdx.x >> 7;    // c-half 0/1
    const float* base = partials + (size_t)r * NTILE * 128 + ri;
    float s = 0.f;
    #pragma unroll
    for (int c = 0; c < 32; ++c)
        s += base[(size_t)(ch * 32 + c) * 128];
    __shared__ float half1[128];
    __shared__ float red[4];
    if (ch == 1) half1[ri] = s;
    __syncthreads();
    float lg = 0.f;
    if (ch == 0) {
        float rs = s + half1[ri];
        int row = r * 128 + ri;
        lg = __logf(rs - __expf(2.0f * diagss[row]));
    }
    #pragma unroll
    for (int off = 32; off; off >>= 1) lg += __shfl_xor(lg, off, 64);
    const int wave = threadIdx.x >> 6, lane = threadIdx.x & 63;
    if (lane == 0) red[wave] = lg;
    __syncthreads();
    if (threadIdx.x == 0) lgpart[r] = red[0] + red[1] + red[2] + red[3];
}

// ---------------------------------------------------------------------------
// Kernel 4: loss = [ sum_r lgpart[r] - 2*sum_k pos_k ] / 8192
// ---------------------------------------------------------------------------
__global__ __launch_bounds__(256) void loss_kernel(
    const float* __restrict__ lgpart, const float* __restrict__ pos,
    float* __restrict__ out)
{
    float local = 0.f;
    if (threadIdx.x < NTILE) local += lgpart[threadIdx.x];
    for (int k = threadIdx.x; k < N_ROWS; k += 256)
        local -= 2.0f * pos[k];
    #pragma unroll
    for (int off = 32; off; off >>= 1) local += __shfl_xor(local, off, 64);
    __shared__ float red[4];
    const int wave = threadIdx.x >> 6, lane = threadIdx.x & 63;
    if (lane == 0) red[wave] = local;
    __syncthreads();
    if (threadIdx.x == 0)
        out[0] = (red[0] + red[1] + red[2] + red[3]) * (1.0f / 8192.0f);
}

// ---------------------------------------------------------------------------
extern "C" void kernel_launch(void* const* d_in, const int* in_sizes, int n_in,
                              void* d_out, int out_size, void* d_ws, size_t ws_size,
                              hipStream_t stream)
{
    const float* emb_i = (const float*)d_in[0];
    const float* emb_j = (const float*)d_in[1];

    // ws layout: zb bf16 [M][D] (8 MB) | partials f32[64][64][128] (2 MB)
    //            | diagss f32[M] | pos f32[N] | lgpart f32[64]  (~10.05 MB)
    unsigned short* zb = (unsigned short*)d_ws;
    float* partials = (float*)((char*)d_ws + (size_t)M * D * sizeof(unsigned short));
    float* diagss   = partials + (size_t)NTILE * NTILE * 128;
    float* pos      = diagss + M;
    float* lgpart   = pos + N_ROWS;
    float* out      = (float*)d_out;

    normpos_kernel<<<N_ROWS / 4, 256, 0, stream>>>(emb_i, emb_j, zb, diagss, pos);
    simgemm_kernel<<<NBLK, 256, 0, stream>>>(zb, partials);
    rowfin_kernel<<<NTILE, 256, 0, stream>>>(partials, diagss, lgpart);
    loss_kernel<<<1, 256, 0, stream>>>(lgpart, pos, out);
}

// Round 7
// 122.368 us; speedup vs baseline: 1.2619x; 1.0295x over previous
//
#include <hip/hip_runtime.h>
#include <cstdint>
#include <cstddef>

// Problem constants (fixed by the reference: N=4096, D=512)
constexpr int N_ROWS = 4096;
constexpr int D      = 512;
constexpr int M      = 8192;   // 2N
constexpr int NTILE  = 64;     // M / 128
constexpr int NBLK   = NTILE * (NTILE + 1) / 2;   // 2080 upper-tri tile pairs
constexpr int LDSOFF = 128 * 32;                  // elems per LDS K-buffer

using f32x4  = __attribute__((ext_vector_type(4))) float;
using bf16x8 = __attribute__((ext_vector_type(8))) __bf16;
using us8    = __attribute__((ext_vector_type(8))) unsigned short;

// RNE float -> bf16 (inputs are finite, no NaN handling needed)
__device__ inline unsigned short f2bf(float f) {
    unsigned int u = __float_as_uint(f);
    u += 0x7fffu + ((u >> 16) & 1u);
    return (unsigned short)(u >> 16);
}
__device__ inline float bf2f(unsigned short s) {
    return __uint_as_float(((unsigned int)s) << 16);
}

// 16B async global->LDS copy. LDS dest is wave-uniform base + lane*16.
#define ASYNC_CP16(gsrc, ldst)                                                      \
    __builtin_amdgcn_global_load_lds(                                               \
        (const __attribute__((address_space(1))) unsigned int*)(gsrc),              \
        (__attribute__((address_space(3))) unsigned int*)(ldst), 16, 0, 0)

// ---------------------------------------------------------------------------
// Kernel 1: fused normalize + positive-pair logits.
// One wave handles PAIR k: row k (emb_i) and row k+N (emb_j).
// ---------------------------------------------------------------------------
__global__ __launch_bounds__(256) void normpos_kernel(
    const float* __restrict__ emb_i, const float* __restrict__ emb_j,
    unsigned short* __restrict__ zb, float* __restrict__ diagss,
    float* __restrict__ pos)
{
    const int wave = threadIdx.x >> 6, lane = threadIdx.x & 63;
    const int k = blockIdx.x * 4 + wave;

    const float4* a = (const float4*)(emb_i + (size_t)k * D);
    const float4* b = (const float4*)(emb_j + (size_t)k * D);
    float4 a0 = a[lane * 2], a1 = a[lane * 2 + 1];
    float4 b0 = b[lane * 2], b1 = b[lane * 2 + 1];

    float ssi = a0.x*a0.x + a0.y*a0.y + a0.z*a0.z + a0.w*a0.w
              + a1.x*a1.x + a1.y*a1.y + a1.z*a1.z + a1.w*a1.w;
    float ssj = b0.x*b0.x + b0.y*b0.y + b0.z*b0.z + b0.w*b0.w
              + b1.x*b1.x + b1.y*b1.y + b1.z*b1.z + b1.w*b1.w;
    float dp  = a0.x*b0.x + a0.y*b0.y + a0.z*b0.z + a0.w*b0.w
              + a1.x*b1.x + a1.y*b1.y + a1.z*b1.z + a1.w*b1.w;
    #pragma unroll
    for (int off = 32; off; off >>= 1) {
        ssi += __shfl_xor(ssi, off, 64);
        ssj += __shfl_xor(ssj, off, 64);
        dp  += __shfl_xor(dp,  off, 64);
    }
    const float invi = rsqrtf(ssi), invj = rsqrtf(ssj);

    const float zi[8] = {a0.x*invi, a0.y*invi, a0.z*invi, a0.w*invi,
                         a1.x*invi, a1.y*invi, a1.z*invi, a1.w*invi};
    const float zj[8] = {b0.x*invj, b0.y*invj, b0.z*invj, b0.w*invj,
                         b1.x*invj, b1.y*invj, b1.z*invj, b1.w*invj};
    us8 pi, pj;
    float dssi = 0.f, dssj = 0.f;
    #pragma unroll
    for (int t = 0; t < 8; ++t) {
        unsigned short bi = f2bf(zi[t]), bj = f2bf(zj[t]);
        pi[t] = bi; pj[t] = bj;
        float fi = bf2f(bi), fj = bf2f(bj);
        dssi += fi * fi; dssj += fj * fj;
    }
    *(us8*)(zb + (size_t)k * D + lane * 8)            = pi;
    *(us8*)(zb + (size_t)(k + N_ROWS) * D + lane * 8) = pj;
    #pragma unroll
    for (int off = 32; off; off >>= 1) {
        dssi += __shfl_xor(dssi, off, 64);
        dssj += __shfl_xor(dssj, off, 64);
    }
    if (lane == 0) {
        diagss[k]          = dssi;
        diagss[k + N_ROWS] = dssj;
        pos[k]             = 2.0f * dp * invi * invj;
    }
}

// ---------------------------------------------------------------------------
// Kernel 2: symmetric fused sim-GEMM + exp + row/col partial sums.
// Upper-triangle tile pairs (bi <= bj), 2080 blocks. 128x128 tile, 4 waves
// 2x2, BK=32 DOUBLE-BUFFERED at 34 KB LDS (keeps 4 blocks/CU, unlike the
// round-4 BK=64 dbuf which halved occupancy). One barrier per iteration;
// prefetch for iter it+1 issues right after the barrier, so the vmcnt(0)
// drain at the next barrier lands after ~300+ cyc of ds_read+MFMA.
// ZERO global atomics (round-3 lesson); wave-halves combined via LDS and
// stored exactly once (round-5 lesson): rows -> partials[bi][bj],
// symmetric cols -> partials[bj][bi].
// ---------------------------------------------------------------------------
__global__ __launch_bounds__(256, 4) void simgemm_kernel(
    const unsigned short* __restrict__ zb, float* __restrict__ partials)
{
    __shared__ unsigned short As[2 * 128 * 32];   // 16 KB x2
    __shared__ unsigned short Bs[2 * 128 * 32];
    __shared__ float rp[4][64];    // per-wave row partials
    __shared__ float cp4[4][64];   // per-wave col partials
    const int tid  = threadIdx.x;
    const int wave = tid >> 6, lane = tid & 63;
    const int l15  = lane & 15, ks = lane >> 4;

    // Decode linear block id -> (bi, bj), bi <= bj. cum(bi) = bi*(129-bi)/2.
    const int t = blockIdx.x;
    int bi = (int)((129.0f - sqrtf(129.0f * 129.0f - 8.0f * (float)t)) * 0.5f);
    while (bi > 0 && bi * (129 - bi) / 2 > t) --bi;
    while ((bi + 1) * (129 - (bi + 1)) / 2 <= t) ++bi;
    const int bj = bi + (t - bi * (129 - bi) / 2);
    const bool diag = (bi == bj);

    const int wrow = (wave >> 1) * 64, wcol = (wave & 1) * 64;

    // Staging mapping: tile = 8 chunks of 1024B (16 rows each); wave w owns
    // chunks {2w, 2w+1}. lane l -> row chunk*16 + (l>>2), phys 16B slot l&3.
    const int ch0 = wave * 2;
    const int sr0 = ch0 * 16 + (lane >> 2);
    const int sc  = ((lane & 3) ^ ((sr0 >> 1) & 3)) * 8;   // swizzled k-offset (elems)
    const unsigned short* gA0 = zb + (size_t)(bi * 128 + sr0) * D + sc;
    const unsigned short* gB0 = zb + (size_t)(bj * 128 + sr0) * D + sc;
    unsigned short* lA = As + ch0 * 512;
    unsigned short* lB = Bs + ch0 * 512;

    // Prime buffer 0 (kc = 0)
    ASYNC_CP16(gA0,          lA);
    ASYNC_CP16(gA0 + 16 * D, lA + 512);
    ASYNC_CP16(gB0,          lB);
    ASYNC_CP16(gB0 + 16 * D, lB + 512);

    f32x4 acc[4][4] = {};
    const int swOff = (ks ^ ((l15 >> 1) & 3)) * 8;  // swizzled frag k-offset (elems)

    #pragma unroll 2
    for (int it = 0; it < D / 32; ++it) {
        __syncthreads();   // vmcnt(0)+lgkmcnt(0): buffer (it&1) ready,
                           // all reads of the other buffer finished.

        if (it + 1 < D / 32) {   // prefetch next K-chunk into other buffer
            const int kc  = (it + 1) * 32;
            const int off = ((it + 1) & 1) * LDSOFF;
            ASYNC_CP16(gA0 + kc,          lA + off);
            ASYNC_CP16(gA0 + kc + 16 * D, lA + off + 512);
            ASYNC_CP16(gB0 + kc,          lB + off);
            ASYNC_CP16(gB0 + kc + 16 * D, lB + off + 512);
        }

        const int cb = (it & 1) * LDSOFF;
        bf16x8 af[4], bg[4];
        #pragma unroll
        for (int f = 0; f < 4; ++f) {
            af[f] = *(const bf16x8*)(As + cb + (wrow + f * 16 + l15) * 32 + swOff);
            bg[f] = *(const bf16x8*)(Bs + cb + (wcol + f * 16 + l15) * 32 + swOff);
        }
        #pragma unroll
        for (int i = 0; i < 4; ++i)
            #pragma unroll
            for (int j = 0; j < 4; ++j)
                acc[i][j] = __builtin_amdgcn_mfma_f32_16x16x32_bf16(
                    af[i], bg[j], acc[i][j], 0, 0, 0);
    }

    // Epilogue. C/D layout: row = ks*4 + r, col = l15 (within each 16x16).
    // e = exp(sim/T) = exp(2*acc). Per-wave partials -> LDS, combine the two
    // waves sharing each row-half / col-half, store exactly once.
    float rowp[4][4] = {};
    #pragma unroll
    for (int j = 0; j < 4; ++j) {
        float cpj = 0.f;
        #pragma unroll
        for (int i = 0; i < 4; ++i)
            #pragma unroll
            for (int r = 0; r < 4; ++r) {
                float e = __expf(2.0f * acc[i][j][r]);
                rowp[i][r] += e;
                cpj += e;
            }
        if (!diag) {
            cpj += __shfl_xor(cpj, 16, 64);
            cpj += __shfl_xor(cpj, 32, 64);
            if (ks == 0) cp4[wave][j * 16 + l15] = cpj;
        }
    }
    #pragma unroll
    for (int i = 0; i < 4; ++i)
        #pragma unroll
        for (int r = 0; r < 4; ++r) {
            float e = rowp[i][r];
            e += __shfl_xor(e, 1, 64);
            e += __shfl_xor(e, 2, 64);
            e += __shfl_xor(e, 4, 64);
            e += __shfl_xor(e, 8, 64);
            if (l15 == 0) rp[wave][i * 16 + ks * 4 + r] = e;
        }
    __syncthreads();

    // rows 0-63 from waves {0,1}, 64-127 from {2,3};
    // cols 0-63 from waves {0,2}, 64-127 from {1,3}.
    float* pA = partials + (size_t)(bi * NTILE + bj) * 128;
    float* pB = partials + (size_t)(bj * NTILE + bi) * 128;
    if (tid < 128) {
        const int h = tid >> 6, rr = tid & 63;
        pA[tid] = rp[h * 2][rr] + rp[h * 2 + 1][rr];
    } else if (!diag) {
        const int c = tid - 128, h = c >> 6, cc = c & 63;
        pB[c] = cp4[h][cc] + cp4[h + 2][cc];
    }
}

// ---------------------------------------------------------------------------
// Kernel 3: per-tile-row reduction of partials + log terms + pos chunk.
// Block r: rowsum[row] = sum_c partials[r][c][row&127];
// lgpart[r] = sum_row log(rowsum - exp(2*diagss)) - 2*sum(pos[r*64..+64)).
// ---------------------------------------------------------------------------
__global__ __launch_bounds__(256) void rowfin_kernel(
    const float* __restrict__ partials, const float* __restrict__ diagss,
    const float* __restrict__ pos, float* __restrict__ lgpart)
{
    const int r  = blockIdx.x;          // tile-row 0..63
    const int ri = threadIdx.x & 127;   // row within tile
    const int ch = threadIdx.x >> 7;    // c-half 0/1
    const float* base = partials + (size_t)r * NTILE * 128 + ri;
    float s = 0.f;
    #pragma unroll
    for (int c = 0; c < 32; ++c)
        s += base[(size_t)(ch * 32 + c) * 128];
    __shared__ float half1[128];
    __shared__ float red[4];
    if (ch == 1) half1[ri] = s;
    __syncthreads();
    float lg = 0.f;
    if (ch == 0) {
        float rs = s + half1[ri];
        int row = r * 128 + ri;
        lg = __logf(rs - __expf(2.0f * diagss[row]));
    }
    if (threadIdx.x < 64)
        lg -= 2.0f * pos[r * 64 + threadIdx.x];
    #pragma unroll
    for (int off = 32; off; off >>= 1) lg += __shfl_xor(lg, off, 64);
    const int wave = threadIdx.x >> 6, lane = threadIdx.x & 63;
    if (lane == 0) red[wave] = lg;
    __syncthreads();
    if (threadIdx.x == 0) lgpart[r] = red[0] + red[1] + red[2] + red[3];
}

// ---------------------------------------------------------------------------
// Kernel 4: loss = sum_r lgpart[r] / 8192   (one wave)
// ---------------------------------------------------------------------------
__global__ __launch_bounds__(64) void loss_kernel(
    const float* __restrict__ lgpart, float* __restrict__ out)
{
    float local = lgpart[threadIdx.x];
    #pragma unroll
    for (int off = 32; off; off >>= 1) local += __shfl_xor(local, off, 64);
    if (threadIdx.x == 0) out[0] = local * (1.0f / 8192.0f);
}

// ---------------------------------------------------------------------------
extern "C" void kernel_launch(void* const* d_in, const int* in_sizes, int n_in,
                              void* d_out, int out_size, void* d_ws, size_t ws_size,
                              hipStream_t stream)
{
    const float* emb_i = (const float*)d_in[0];
    const float* emb_j = (const float*)d_in[1];

    // ws layout: zb bf16 [M][D] (8 MB) | partials f32[64][64][128] (2 MB)
    //            | diagss f32[M] | pos f32[N] | lgpart f32[64]  (~10.05 MB)
    unsigned short* zb = (unsigned short*)d_ws;
    float* partials = (float*)((char*)d_ws + (size_t)M * D * sizeof(unsigned short));
    float* diagss   = partials + (size_t)NTILE * NTILE * 128;
    float* pos      = diagss + M;
    float* lgpart   = pos + N_ROWS;
    float* out      = (float*)d_out;

    normpos_kernel<<<N_ROWS / 4, 256, 0, stream>>>(emb_i, emb_j, zb, diagss, pos);
    simgemm_kernel<<<NBLK, 256, 0, stream>>>(zb, partials);
    rowfin_kernel<<<NTILE, 256, 0, stream>>>(partials, diagss, pos, lgpart);
    loss_kernel<<<1, 64, 0, stream>>>(lgpart, out);
}

// Round 9
// 103.622 us; speedup vs baseline: 1.4902x; 1.1809x over previous
//
#include <hip/hip_runtime.h>
#include <cstdint>
#include <cstddef>

// Problem constants (fixed by the reference: N=4096, D=512)
constexpr int N_ROWS = 4096;
constexpr int D      = 512;
constexpr int M      = 8192;   // 2N
constexpr int NTILE  = 64;     // M / 128
constexpr int NBLK   = NTILE * (NTILE + 1) / 2;   // 2080 upper-tri tile pairs
constexpr int BKB    = 64;                        // K-bytes per iter (fp8, K=64)
constexpr int LDSB   = 128 * BKB;                 // bytes per LDS K-buffer (8 KB)

using f32x4 = __attribute__((ext_vector_type(4))) float;
using ul2   = __attribute__((ext_vector_type(2))) unsigned long;

// 16B async global->LDS copy. LDS dest is wave-uniform base + lane*16.
#define ASYNC_CP16(gsrc, ldst)                                                      \
    __builtin_amdgcn_global_load_lds(                                               \
        (const __attribute__((address_space(1))) unsigned int*)(gsrc),              \
        (__attribute__((address_space(3))) unsigned int*)(ldst), 16, 0, 0)

// sum of squares of the 4 fp8 e4m3 bytes in `pk` (selector must be literal)
#define SS_FP8(pk, accum)                                                           \
    do {                                                                            \
        float f0 = __builtin_amdgcn_cvt_f32_fp8((pk), 0);                           \
        float f1 = __builtin_amdgcn_cvt_f32_fp8((pk), 1);                           \
        float f2 = __builtin_amdgcn_cvt_f32_fp8((pk), 2);                           \
        float f3 = __builtin_amdgcn_cvt_f32_fp8((pk), 3);                           \
        (accum) += f0 * f0 + f1 * f1 + f2 * f2 + f3 * f3;                           \
    } while (0)

// ---------------------------------------------------------------------------
// Kernel 1: fused normalize + fp8-quantize + positive-pair logits.
// One wave handles PAIR k: row k (emb_i) and row k+N (emb_j).
// Z rows are stored fp8 e4m3 with a per-64B-block K-group permutation
// [0,4,1,5,2,6,3,7] so one ds_read_b128 in the GEMM yields both K-halves
// of two mfma_16x16x32_fp8 fragments. diagss is computed from the
// QUANTIZED values (matches the MFMA diagonal); pos stays fp32-exact.
// ---------------------------------------------------------------------------
__global__ __launch_bounds__(256) void normpos_kernel(
    const float* __restrict__ emb_i, const float* __restrict__ emb_j,
    uint8_t* __restrict__ zb, float* __restrict__ diagss,
    float* __restrict__ pos)
{
    const int wave = threadIdx.x >> 6, lane = threadIdx.x & 63;
    const int k = blockIdx.x * 4 + wave;

    const float4* a = (const float4*)(emb_i + (size_t)k * D);
    const float4* b = (const float4*)(emb_j + (size_t)k * D);
    float4 a0 = a[lane * 2], a1 = a[lane * 2 + 1];
    float4 b0 = b[lane * 2], b1 = b[lane * 2 + 1];

    float ssi = a0.x*a0.x + a0.y*a0.y + a0.z*a0.z + a0.w*a0.w
              + a1.x*a1.x + a1.y*a1.y + a1.z*a1.z + a1.w*a1.w;
    float ssj = b0.x*b0.x + b0.y*b0.y + b0.z*b0.z + b0.w*b0.w
              + b1.x*b1.x + b1.y*b1.y + b1.z*b1.z + b1.w*b1.w;
    float dp  = a0.x*b0.x + a0.y*b0.y + a0.z*b0.z + a0.w*b0.w
              + a1.x*b1.x + a1.y*b1.y + a1.z*b1.z + a1.w*b1.w;
    #pragma unroll
    for (int off = 32; off; off >>= 1) {
        ssi += __shfl_xor(ssi, off, 64);
        ssj += __shfl_xor(ssj, off, 64);
        dp  += __shfl_xor(dp,  off, 64);
    }
    const float invi = rsqrtf(ssi), invj = rsqrtf(ssj);

    const float zi[8] = {a0.x*invi, a0.y*invi, a0.z*invi, a0.w*invi,
                         a1.x*invi, a1.y*invi, a1.z*invi, a1.w*invi};
    const float zj[8] = {b0.x*invj, b0.y*invj, b0.z*invj, b0.w*invj,
                         b1.x*invj, b1.y*invj, b1.z*invj, b1.w*invj};

    // quantize to fp8 e4m3 (HW RNE + subnormals), dequant for diag sumsq
    int pi0 = __builtin_amdgcn_cvt_pk_fp8_f32(zi[0], zi[1], 0, false);
    pi0     = __builtin_amdgcn_cvt_pk_fp8_f32(zi[2], zi[3], pi0, true);
    int pi1 = __builtin_amdgcn_cvt_pk_fp8_f32(zi[4], zi[5], 0, false);
    pi1     = __builtin_amdgcn_cvt_pk_fp8_f32(zi[6], zi[7], pi1, true);
    int pj0 = __builtin_amdgcn_cvt_pk_fp8_f32(zj[0], zj[1], 0, false);
    pj0     = __builtin_amdgcn_cvt_pk_fp8_f32(zj[2], zj[3], pj0, true);
    int pj1 = __builtin_amdgcn_cvt_pk_fp8_f32(zj[4], zj[5], 0, false);
    pj1     = __builtin_amdgcn_cvt_pk_fp8_f32(zj[6], zj[7], pj1, true);

    float dssi = 0.f, dssj = 0.f;
    SS_FP8(pi0, dssi);
    SS_FP8(pi1, dssi);
    SS_FP8(pj0, dssj);
    SS_FP8(pj1, dssj);

    // permuted store: lane = K-group g (8 fp8); block b = g>>3 holds 8 groups
    // at slots [0,4,1,5,2,6,3,7] -> group w goes to slot 2w (w<4) / 2(w-4)+1.
    const int g = lane, bb = g >> 3, w = g & 7;
    const int sl = bb * 8 + ((w < 4) ? (w * 2) : ((w - 4) * 2 + 1));
    const unsigned long long vi =
        ((unsigned long long)(unsigned)pi1 << 32) | (unsigned)pi0;
    const unsigned long long vj =
        ((unsigned long long)(unsigned)pj1 << 32) | (unsigned)pj0;
    *(unsigned long long*)(zb + (size_t)k * D + sl * 8)            = vi;
    *(unsigned long long*)(zb + (size_t)(k + N_ROWS) * D + sl * 8) = vj;

    #pragma unroll
    for (int off = 32; off; off >>= 1) {
        dssi += __shfl_xor(dssi, off, 64);
        dssj += __shfl_xor(dssj, off, 64);
    }
    if (lane == 0) {
        diagss[k]          = dssi;
        diagss[k + N_ROWS] = dssj;
        pos[k]             = 2.0f * dp * invi * invj;
    }
}

// ---------------------------------------------------------------------------
// Kernel 2: symmetric fused sim-GEMM (fp8 e4m3) + exp + row/col partials.
// Upper-triangle tile pairs (bi <= bj), 2080 blocks. 128x128 tile, 4 waves
// 2x2, BK=64 (fp8 bytes = 64/row/iter), double-buffered at 34 KB LDS
// (4 blocks/CU). 8 iterations -> half the barrier drains of the bf16
// version, with 32 MFMA of compute per barrier. One ds_read_b128 feeds
// both K-halves (permuted Z layout). ZERO global atomics; wave-halves
// combined via LDS, stored exactly once (rows -> partials[bi][bj],
// symmetric cols -> partials[bj][bi]).
// ---------------------------------------------------------------------------
__global__ __launch_bounds__(256, 4) void simgemm_kernel(
    const uint8_t* __restrict__ zb, float* __restrict__ partials)
{
    __shared__ ul2 AsV[2 * LDSB / 16];   // 16 KB (2 bufs x 8 KB), 16B aligned
    __shared__ ul2 BsV[2 * LDSB / 16];
    __shared__ float rp[4][64];    // per-wave row partials
    __shared__ float cp4[4][64];   // per-wave col partials
    uint8_t* As = (uint8_t*)AsV;
    uint8_t* Bs = (uint8_t*)BsV;

    const int tid  = threadIdx.x;
    const int wave = tid >> 6, lane = tid & 63;
    const int l15  = lane & 15, ks = lane >> 4;

    // Decode linear block id -> (bi, bj), bi <= bj. cum(bi) = bi*(129-bi)/2.
    const int t = blockIdx.x;
    int bi = (int)((129.0f - sqrtf(129.0f * 129.0f - 8.0f * (float)t)) * 0.5f);
    while (bi > 0 && bi * (129 - bi) / 2 > t) --bi;
    while ((bi + 1) * (129 - (bi + 1)) / 2 <= t) ++bi;
    const int bj = bi + (t - bi * (129 - bi) / 2);
    const bool diag = (bi == bj);

    const int wrow = (wave >> 1) * 64, wcol = (wave & 1) * 64;

    // Staging: wave w owns rows [w*32, w*32+32): two ASYNCs per matrix per
    // iter (16 rows each). lane l -> row (l>>2), phys 16B chunk l&3; source
    // logical chunk = (l&3) ^ ((l>>3)&3)  (same swizzle family as bf16
    // rounds, measured 0 conflicts).
    const int srow = wave * 32 + (lane >> 2);
    const int scol = ((lane & 3) ^ ((lane >> 3) & 3)) * 16;   // bytes in [0,64)
    const uint8_t* gA = zb + (size_t)(bi * 128 + srow) * D + scol;
    const uint8_t* gB = zb + (size_t)(bj * 128 + srow) * D + scol;
    uint8_t* lA = As + wave * 32 * BKB;   // + it-buffer offset
    uint8_t* lB = Bs + wave * 32 * BKB;

    // Prime buffer 0 (K-bytes [0,64))
    ASYNC_CP16(gA,            lA);
    ASYNC_CP16(gA + 16 * D,   lA + 16 * BKB);
    ASYNC_CP16(gB,            lB);
    ASYNC_CP16(gB + 16 * D,   lB + 16 * BKB);

    f32x4 acc[4][4] = {};
    const int swb = (ks ^ ((l15 >> 1) & 3)) * 16;   // frag byte offset in row

    for (int it = 0; it < D / BKB; ++it) {
        __syncthreads();   // buffer (it&1) ready; other buffer's reads done

        if (it + 1 < D / BKB) {   // prefetch next K-chunk into other buffer
            const int kc  = (it + 1) * BKB;
            const int off = ((it + 1) & 1) * LDSB;
            ASYNC_CP16(gA + kc,          lA + off);
            ASYNC_CP16(gA + kc + 16 * D, lA + off + 16 * BKB);
            ASYNC_CP16(gB + kc,          lB + off);
            ASYNC_CP16(gB + kc + 16 * D, lB + off + 16 * BKB);
        }

        const int cb = (it & 1) * LDSB;
        ul2 af[4], bg[4];
        #pragma unroll
        for (int f = 0; f < 4; ++f) {
            af[f] = *(const ul2*)(As + cb + (wrow + f * 16 + l15) * BKB + swb);
            bg[f] = *(const ul2*)(Bs + cb + (wcol + f * 16 + l15) * BKB + swb);
        }
        #pragma unroll
        for (int i = 0; i < 4; ++i)
            #pragma unroll
            for (int j = 0; j < 4; ++j) {
                acc[i][j] = __builtin_amdgcn_mfma_f32_16x16x32_fp8_fp8(
                    (long)af[i][0], (long)bg[j][0], acc[i][j], 0, 0, 0);
                acc[i][j] = __builtin_amdgcn_mfma_f32_16x16x32_fp8_fp8(
                    (long)af[i][1], (long)bg[j][1], acc[i][j], 0, 0, 0);
            }
    }

    // Epilogue. C/D layout: row = ks*4 + r, col = l15 (within each 16x16).
    // e = exp(sim/T) = exp(2*acc). Per-wave partials -> LDS, combine the two
    // waves sharing each row-half / col-half, store exactly once.
    float rowp[4][4] = {};
    #pragma unroll
    for (int j = 0; j < 4; ++j) {
        float cpj = 0.f;
        #pragma unroll
        for (int i = 0; i < 4; ++i)
            #pragma unroll
            for (int r = 0; r < 4; ++r) {
                float e = __expf(2.0f * acc[i][j][r]);
                rowp[i][r] += e;
                cpj += e;
            }
        if (!diag) {
            cpj += __shfl_xor(cpj, 16, 64);
            cpj += __shfl_xor(cpj, 32, 64);
            if (ks == 0) cp4[wave][j * 16 + l15] = cpj;
        }
    }
    #pragma unroll
    for (int i = 0; i < 4; ++i)
        #pragma unroll
        for (int r = 0; r < 4; ++r) {
            float e = rowp[i][r];
            e += __shfl_xor(e, 1, 64);
            e += __shfl_xor(e, 2, 64);
            e += __shfl_xor(e, 4, 64);
            e += __shfl_xor(e, 8, 64);
            if (l15 == 0) rp[wave][i * 16 + ks * 4 + r] = e;
        }
    __syncthreads();

    // rows 0-63 from waves {0,1}, 64-127 from {2,3};
    // cols 0-63 from waves {0,2}, 64-127 from {1,3}.
    float* pA = partials + (size_t)(bi * NTILE + bj) * 128;
    float* pB = partials + (size_t)(bj * NTILE + bi) * 128;
    if (tid < 128) {
        const int h = tid >> 6, rr = tid & 63;
        pA[tid] = rp[h * 2][rr] + rp[h * 2 + 1][rr];
    } else if (!diag) {
        const int c = tid - 128, h = c >> 6, cc = c & 63;
        pB[c] = cp4[h][cc] + cp4[h + 2][cc];
    }
}

// ---------------------------------------------------------------------------
// Kernel 3: per-tile-row reduction of partials + log terms + pos chunk.
// ---------------------------------------------------------------------------
__global__ __launch_bounds__(256) void rowfin_kernel(
    const float* __restrict__ partials, const float* __restrict__ diagss,
    const float* __restrict__ pos, float* __restrict__ lgpart)
{
    const int r  = blockIdx.x;          // tile-row 0..63
    const int ri = threadIdx.x & 127;   // row within tile
    const int ch = threadIdx.x >> 7;    // c-half 0/1
    const float* base = partials + (size_t)r * NTILE * 128 + ri;
    float s = 0.f;
    #pragma unroll
    for (int c = 0; c < 32; ++c)
        s += base[(size_t)(ch * 32 + c) * 128];
    __shared__ float half1[128];
    __shared__ float red[4];
    if (ch == 1) half1[ri] = s;
    __syncthreads();
    float lg = 0.f;
    if (ch == 0) {
        float rs = s + half1[ri];
        int row = r * 128 + ri;
        lg = __logf(rs - __expf(2.0f * diagss[row]));
    }
    if (threadIdx.x < 64)
        lg -= 2.0f * pos[r * 64 + threadIdx.x];
    #pragma unroll
    for (int off = 32; off; off >>= 1) lg += __shfl_xor(lg, off, 64);
    const int wave = threadIdx.x >> 6, lane = threadIdx.x & 63;
    if (lane == 0) red[wave] = lg;
    __syncthreads();
    if (threadIdx.x == 0) lgpart[r] = red[0] + red[1] + red[2] + red[3];
}

// ---------------------------------------------------------------------------
// Kernel 4: loss = sum_r lgpart[r] / 8192   (one wave)
// ---------------------------------------------------------------------------
__global__ __launch_bounds__(64) void loss_kernel(
    const float* __restrict__ lgpart, float* __restrict__ out)
{
    float local = lgpart[threadIdx.x];
    #pragma unroll
    for (int off = 32; off; off >>= 1) local += __shfl_xor(local, off, 64);
    if (threadIdx.x == 0) out[0] = local * (1.0f / 8192.0f);
}

// ---------------------------------------------------------------------------
extern "C" void kernel_launch(void* const* d_in, const int* in_sizes, int n_in,
                              void* d_out, int out_size, void* d_ws, size_t ws_size,
                              hipStream_t stream)
{
    const float* emb_i = (const float*)d_in[0];
    const float* emb_j = (const float*)d_in[1];

    // ws layout: zb fp8 [M][D] (4 MB) | partials f32[64][64][128] (2 MB)
    //            | diagss f32[M] | pos f32[N] | lgpart f32[64]  (~6.05 MB)
    uint8_t* zb = (uint8_t*)d_ws;
    float* partials = (float*)((char*)d_ws + (size_t)M * D);
    float* diagss   = partials + (size_t)NTILE * NTILE * 128;
    float* pos      = diagss + M;
    float* lgpart   = pos + N_ROWS;
    float* out      = (float*)d_out;

    normpos_kernel<<<N_ROWS / 4, 256, 0, stream>>>(emb_i, emb_j, zb, diagss, pos);
    simgemm_kernel<<<NBLK, 256, 0, stream>>>(zb, partials);
    rowfin_kernel<<<NTILE, 256, 0, stream>>>(partials, diagss, pos, lgpart);
    loss_kernel<<<1, 64, 0, stream>>>(lgpart, out);
}